// Round 4
// baseline (509.367 us; speedup 1.0000x reference)
//
#include <hip/hip_runtime.h>
#include <hip/hip_bf16.h>

#define NN 50000
#define EE 800000
#define IND 64
#define HD 128

#define KCH 32            // edge chunks [R4: 64->32, halves PD/PS + start traffic]
#define CHUNK 25000       // EE / KCH (max count 25000 fits u16)
#define NPART 4           // node partitions
#define PART_N 12500      // NN / NPART
#define PWORDS 6250       // PART_N / 2 (16-bit packed pairs)
#define NB 196            // ceil(NN/256)

#define GQB 391           // gather: grid = 8*GQB = 3128; 782 blocks/quarter, 64 nodes/block

typedef __hip_bfloat16 bf16;
typedef _Float16 fp16;
typedef _Float16 half8 __attribute__((ext_vector_type(8)));
typedef short short8 __attribute__((ext_vector_type(8)));
typedef __attribute__((ext_vector_type(4))) float f32x4;

__device__ __forceinline__ float loadT(const void* p, size_t i, int f32) {
    if (f32) return ((const float*)p)[i];
    return __bfloat162float(((const bf16*)p)[i]);
}

__device__ __forceinline__ float b2f_raw(short s) {
    return __uint_as_float(((unsigned int)(unsigned short)s) << 16);
}

// flag=1 if float inputs are fp32, flag=0 if bf16.
__global__ void detect_kernel(const unsigned short* __restrict__ xraw,
                              int* __restrict__ flag) {
    if (threadIdx.x == 0) {
        int f = 0;
        for (int i = 0; i < 256; i += 2) {
            unsigned int w = ((unsigned int)xraw[i]) << 16;
            float a = fabsf(__uint_as_float(w));
            if (!(a <= 1.0e6f)) f = 1;
        }
        *flag = f;
    }
}

__global__ void fill_sentinel(bf16* __restrict__ out, int n) {
    int i = blockIdx.x * 256 + threadIdx.x;
    if (i < n) out[i] = __float2bfloat16(0.123f);
}

// One-time weight convert+transpose to fp16: WpT[col][k] (128x64) then
// WlT[l][col][k] (3 x 128x128). Total 57344 fp16 = 114KB, L2-resident after.
__global__ __launch_bounds__(256) void wconv_kernel(const void* __restrict__ Wp,
                                                    const void* __restrict__ Wl,
                                                    const int* __restrict__ flag,
                                                    fp16* __restrict__ wbuf) {
    int f32 = *flag;
    int i = blockIdx.x * 256 + threadIdx.x;
    if (i < 8192) {
        int col = i >> 6, k = i & 63;
        wbuf[col * 64 + k] = (fp16)loadT(Wp, (size_t)k * 128 + col, f32);
    } else if (i < 57344) {
        int j = i - 8192;
        int l = j >> 14;
        int r = j & 16383;
        int col = r >> 7, k = r & 127;
        wbuf[8192 + l * 16384 + col * 128 + k] =
            (fp16)loadT(Wl, (size_t)l * 16384 + (size_t)k * 128 + col, f32);
    }
}

// Chunked LDS histograms, zero global atomics. [R11-proven; R3's global-atomic
// variant was 10x slower — device-scope atomics serialize across XCDs]
__global__ __launch_bounds__(256) void histA_kernel(const int* __restrict__ src,
                                                    const int* __restrict__ dst,
                                                    unsigned* __restrict__ PD,
                                                    unsigned* __restrict__ PS) {
    int b = blockIdx.x;
    int stream = b >> 7;               // NPART*KCH = 128 blocks per stream
    int part = (b >> 5) & 3;
    int k = b & 31;
    const int* ebuf = stream ? src : dst;
    unsigned* out = (stream ? PS : PD) + (size_t)(k * NPART + part) * PWORDS;
    __shared__ unsigned sh[PWORDS];
    for (int w = threadIdx.x; w < PWORDS; w += 256) sh[w] = 0;
    __syncthreads();
    int base = k * CHUNK;
    int pb = part * PART_N;
    for (int i = threadIdx.x; i < CHUNK; i += 256) {
        int n = ebuf[base + i];
        unsigned r = (unsigned)(n - pb);
        if (r < PART_N)
            atomicAdd(&sh[r >> 1], 1u << ((r & 1) * 16));
    }
    __syncthreads();
    for (int w = threadIdx.x; w < PWORDS; w += 256) out[w] = sh[w];
}

// Sum chunk partials -> degrees -> norms (+ raw in-degree for the sorter);
// block-scan deg_in; raw block totals to bsum.
__global__ __launch_bounds__(256) void normscanB_kernel(const unsigned* __restrict__ PD,
                                                        const unsigned* __restrict__ PS,
                                                        float* __restrict__ norm_src,
                                                        float* __restrict__ norm_dst,
                                                        int* __restrict__ degw,
                                                        int* __restrict__ row_ofs,
                                                        int* __restrict__ bsum) {
    __shared__ int sm[256];
    int t = threadIdx.x;
    int i = blockIdx.x * 256 + t;
    int d = 0;
    if (i < NN) {
        int part = i / PART_N;
        unsigned r = (unsigned)(i - part * PART_N);
        int w = r >> 1, shf = (r & 1) * 16;
        int s = 0;
#pragma unroll
        for (int k = 0; k < KCH; ++k) {
            d += (PD[(size_t)(k * NPART + part) * PWORDS + w] >> shf) & 0xffff;
            s += (PS[(size_t)(k * NPART + part) * PWORDS + w] >> shf) & 0xffff;
        }
        norm_src[i] = rsqrtf((float)(s < 1 ? 1 : s));
        norm_dst[i] = rsqrtf((float)(d < 1 ? 1 : d));
        degw[i] = d;
    }
    sm[t] = d;
    __syncthreads();
    for (int ofs = 1; ofs < 256; ofs <<= 1) {
        int add = (t >= ofs) ? sm[t - ofs] : 0;
        __syncthreads();
        sm[t] += add;
        __syncthreads();
    }
    if (i < NN) row_ofs[i] = sm[t] - d;
    if (t == 255) bsum[blockIdx.x] = sm[255];
}

// One-block LDS counting sort of nodes by in-degree (clamped 255). Gather
// processes nodes in this order so each wave's 16 nodes have ~equal degree
// (kills the E[max16 Poisson]/mean ~1.5x divergence waste). [R4]
__global__ __launch_bounds__(256) void dsort_kernel(const int* __restrict__ deg,
                                                    int* __restrict__ order) {
    __shared__ int hist[256];
    __shared__ int sc[256];
    __shared__ int cur[256];
    int t = threadIdx.x;
    hist[t] = 0;
    __syncthreads();
    for (int i = t; i < NN; i += 256) {
        int d = deg[i];
        if (d > 255) d = 255;
        atomicAdd(&hist[d], 1);
    }
    __syncthreads();
    sc[t] = hist[t];
    __syncthreads();
    for (int ofs = 1; ofs < 256; ofs <<= 1) {
        int add = (t >= ofs) ? sc[t - ofs] : 0;
        __syncthreads();
        sc[t] += add;
        __syncthreads();
    }
    cur[t] = sc[t] - hist[t];   // exclusive prefix = bin start
    __syncthreads();
    for (int i = t; i < NN; i += 256) {
        int d = deg[i];
        if (d > 255) d = 255;
        int pos = atomicAdd(&cur[d], 1);
        order[pos] = i;
    }
}

// Finalize row_ofs (self-computed block prefix over bsum);
// emit per-chunk absolute bucket cursors start[k][n].
__global__ __launch_bounds__(256) void scan3_kernel(int* __restrict__ row_ofs,
                                                    const int* __restrict__ bsum,
                                                    const unsigned* __restrict__ PD,
                                                    int* __restrict__ start) {
    __shared__ int sp[256];
    int t = threadIdx.x;
    sp[t] = (t < NB && t < (int)blockIdx.x) ? bsum[t] : 0;
    __syncthreads();
    for (int o = 128; o > 0; o >>= 1) {
        if (t < o) sp[t] += sp[t + o];
        __syncthreads();
    }
    int pref = sp[0];
    int i = blockIdx.x * 256 + t;
    if (i < NN) {
        int v = row_ofs[i] + pref;
        row_ofs[i] = v;
        int part = i / PART_N;
        unsigned r = (unsigned)(i - part * PART_N);
        int w = r >> 1, shf = (r & 1) * 16;
        int run = v;
#pragma unroll
        for (int k = 0; k < KCH; ++k) {
            start[(size_t)k * NN + i] = run;
            run += (PD[(size_t)(k * NPART + part) * PWORDS + w] >> shf) & 0xffff;
        }
    }
    if (i == 0) row_ofs[NN] = EE;
}

// CSR placement via LDS rank; no global atomics. [R11-proven]
__global__ __launch_bounds__(256) void placeC_kernel(const int* __restrict__ src,
                                                     const int* __restrict__ dst,
                                                     const int* __restrict__ start,
                                                     int* __restrict__ csr_src) {
    int b = blockIdx.x;
    int part = b >> 5;
    int k = b & 31;
    __shared__ unsigned sh[PWORDS];
    for (int w = threadIdx.x; w < PWORDS; w += 256) sh[w] = 0;
    __syncthreads();
    int base = k * CHUNK;
    int pb = part * PART_N;
    for (int i = threadIdx.x; i < CHUNK; i += 256) {
        int n = dst[base + i];
        unsigned r = (unsigned)(n - pb);
        if (r < PART_N) {
            unsigned shf = (r & 1) * 16;
            unsigned old = atomicAdd(&sh[r >> 1], 1u << shf);
            int local = (int)((old >> shf) & 0xffff);
            int pos = start[(size_t)k * NN + n] + local;
            csr_src[pos] = src[base + i];
        }
    }
}

// LDS-free MFMA proj: h = fp16(relu(x @ Wp + bp)). 64 rows/block, 4 waves.
__global__ __launch_bounds__(256) void proj_kernel(const void* __restrict__ x,
                                                   const fp16* __restrict__ wpT,
                                                   const void* __restrict__ bp,
                                                   const int* __restrict__ flag,
                                                   fp16* __restrict__ h) {
    int f32 = *flag;
    int tid = threadIdx.x;
    int w = tid >> 6;
    int lane = tid & 63;
    int m = lane & 15;
    int q = lane >> 4;
    int row0 = blockIdx.x * 64 + w * 16;

    int rowA = row0 + m;
    if (rowA > NN - 1) rowA = NN - 1;
    half8 a0, a1;
    if (!f32) {
        short8 r0 = *(const short8*)((const short*)x + (size_t)rowA * IND + q * 8);
        short8 r1 = *(const short8*)((const short*)x + (size_t)rowA * IND + 32 + q * 8);
#pragma unroll
        for (int j = 0; j < 8; ++j) {
            a0[j] = (fp16)b2f_raw(r0[j]);
            a1[j] = (fp16)b2f_raw(r1[j]);
        }
    } else {
#pragma unroll
        for (int j = 0; j < 8; ++j) {
            a0[j] = (fp16)((const float*)x)[(size_t)rowA * IND + q * 8 + j];
            a1[j] = (fp16)((const float*)x)[(size_t)rowA * IND + 32 + q * 8 + j];
        }
    }

#pragma unroll
    for (int t = 0; t < 8; ++t) {
        int col = t * 16 + m;
        const fp16* bt = wpT + (size_t)col * 64 + q * 8;
        f32x4 c = {0.f, 0.f, 0.f, 0.f};
        c = __builtin_amdgcn_mfma_f32_16x16x32_f16(a0, *(const half8*)bt, c, 0, 0, 0);
        c = __builtin_amdgcn_mfma_f32_16x16x32_f16(a1, *(const half8*)(bt + 32), c, 0, 0, 0);
        float bv = loadT(bp, col, f32);
#pragma unroll
        for (int r = 0; r < 4; ++r) {
            int row = row0 + q * 4 + r;
            if (row < NN)
                h[(size_t)row * HD + col] = (fp16)fmaxf(c[r] + bv, 0.f);
        }
    }
}

// LDS-free MFMA pgemm: p4[quarter][row][0..31] = norm_src[row] * (h[row,:] @ Wl),
// column-quartered layout. col = t*16+m -> quarter = t>>1, within = (t&1)*16+m.
__global__ __launch_bounds__(256) void pgemm_kernel(const fp16* __restrict__ h,
                                                    const fp16* __restrict__ wT,
                                                    const float* __restrict__ norm_src,
                                                    fp16* __restrict__ p) {
    int tid = threadIdx.x;
    int w = tid >> 6;
    int lane = tid & 63;
    int m = lane & 15;
    int q = lane >> 4;
    int row0 = blockIdx.x * 64 + w * 16;

    int rowA = row0 + m;
    if (rowA > NN - 1) rowA = NN - 1;
    const fp16* Arow = h + (size_t)rowA * 128 + q * 8;
    half8 a[4];
#pragma unroll
    for (int kk = 0; kk < 4; ++kk) a[kk] = *(const half8*)(Arow + kk * 32);

    float ns[4];
#pragma unroll
    for (int r = 0; r < 4; ++r) {
        int row = row0 + q * 4 + r;
        ns[r] = norm_src[row < NN ? row : NN - 1];
    }

#pragma unroll
    for (int t = 0; t < 8; ++t) {
        int col = t * 16 + m;
        const fp16* bt = wT + (size_t)col * 128 + q * 8;
        f32x4 c = {0.f, 0.f, 0.f, 0.f};
#pragma unroll
        for (int kk = 0; kk < 4; ++kk) {
            half8 b = *(const half8*)(bt + kk * 32);
            c = __builtin_amdgcn_mfma_f32_16x16x32_f16(a[kk], b, c, 0, 0, 0);
        }
        size_t qbase = ((size_t)(t >> 1) * NN) * 32 + (size_t)((t & 1) * 16 + m);
#pragma unroll
        for (int r = 0; r < 4; ++r) {
            int row = row0 + q * 4 + r;
            if (row < NN)
                p[qbase + (size_t)row * 32] = (fp16)(c[r] * ns[r]);
        }
    }
}

// Quartered gather over DEGREE-SORTED node order: waves get degree-uniform
// node groups -> minimal masked-lane waste in the edge loop. [R4]
__global__ __launch_bounds__(256) void gather_kernel(const fp16* __restrict__ p,
                                                     const int* __restrict__ row_ofs,
                                                     const int* __restrict__ csr_src,
                                                     const int* __restrict__ order,
                                                     const float* __restrict__ norm_dst,
                                                     const void* __restrict__ bias,
                                                     int bofs,
                                                     const int* __restrict__ flag,
                                                     fp16* __restrict__ h_out,
                                                     void* __restrict__ outv,
                                                     int is_final) {
    int f32 = *flag;
    int bid = blockIdx.x;
    int s8 = bid & 7;
    int q = s8 >> 1;
    int nodeblock = (bid >> 3) * 2 + (s8 & 1);
    int g = threadIdx.x >> 2;
    int c = threadIdx.x & 3;
    int pos = nodeblock * 64 + g;
    if (pos >= NN) return;
    int n = order[pos];

    const fp16* pq = p + ((size_t)q * NN) * 32 + c * 8;
    int e0 = row_ofs[n];
    int e1 = row_ofs[n + 1];
    float acc[8] = {0.f, 0.f, 0.f, 0.f, 0.f, 0.f, 0.f, 0.f};
    int e = e0;
    for (; e + 7 < e1; e += 8) {
        int s[8];
#pragma unroll
        for (int u = 0; u < 8; ++u) s[u] = __builtin_nontemporal_load(csr_src + e + u);
        half8 v[8];
#pragma unroll
        for (int u = 0; u < 8; ++u)
            v[u] = *(const half8*)(pq + (size_t)s[u] * 32);
#pragma unroll
        for (int j = 0; j < 8; ++j)
            acc[j] += (((float)v[0][j] + (float)v[1][j]) + ((float)v[2][j] + (float)v[3][j])) +
                      (((float)v[4][j] + (float)v[5][j]) + ((float)v[6][j] + (float)v[7][j]));
    }
    for (; e + 3 < e1; e += 4) {
        int s0 = __builtin_nontemporal_load(csr_src + e);
        int s1 = __builtin_nontemporal_load(csr_src + e + 1);
        int s2 = __builtin_nontemporal_load(csr_src + e + 2);
        int s3 = __builtin_nontemporal_load(csr_src + e + 3);
        half8 v0 = *(const half8*)(pq + (size_t)s0 * 32);
        half8 v1 = *(const half8*)(pq + (size_t)s1 * 32);
        half8 v2 = *(const half8*)(pq + (size_t)s2 * 32);
        half8 v3 = *(const half8*)(pq + (size_t)s3 * 32);
#pragma unroll
        for (int j = 0; j < 8; ++j)
            acc[j] += ((float)v0[j] + (float)v1[j]) + ((float)v2[j] + (float)v3[j]);
    }
    for (; e < e1; ++e) {
        int s0 = __builtin_nontemporal_load(csr_src + e);
        half8 v0 = *(const half8*)(pq + (size_t)s0 * 32);
#pragma unroll
        for (int j = 0; j < 8; ++j) acc[j] += (float)v0[j];
    }

    float nd = norm_dst[n];
    int colbase = q * 32 + c * 8;
    size_t base = (size_t)n * HD + colbase;
    if (is_final) {
        if (f32) {
            f32x4 o0, o1;
#pragma unroll
            for (int j = 0; j < 4; ++j) {
                float bv = loadT(bias, (size_t)bofs + colbase + j, f32);
                o0[j] = fmaxf(acc[j] * nd + bv, 0.0f);
            }
#pragma unroll
            for (int j = 0; j < 4; ++j) {
                float bv = loadT(bias, (size_t)bofs + colbase + 4 + j, f32);
                o1[j] = fmaxf(acc[4 + j] * nd + bv, 0.0f);
            }
            __builtin_nontemporal_store(o0, (f32x4*)((float*)outv + base));
            __builtin_nontemporal_store(o1, (f32x4*)((float*)outv + base + 4));
        } else {
            short8 ov;
#pragma unroll
            for (int j = 0; j < 8; ++j) {
                float bv = loadT(bias, (size_t)bofs + colbase + j, f32);
                bf16 t = __float2bfloat16(fmaxf(acc[j] * nd + bv, 0.0f));
                ov[j] = *reinterpret_cast<short*>(&t);
            }
            __builtin_nontemporal_store(ov, (short8*)((bf16*)outv + base));
        }
    } else {
        half8 hv;
#pragma unroll
        for (int j = 0; j < 8; ++j) {
            float bv = loadT(bias, (size_t)bofs + colbase + j, f32);
            hv[j] = (fp16)fmaxf(acc[j] * nd + bv, 0.0f);
        }
        __builtin_nontemporal_store(hv, (half8*)(h_out + base));
    }
}

extern "C" void kernel_launch(void* const* d_in, const int* in_sizes, int n_in,
                              void* d_out, int out_size, void* d_ws, size_t ws_size,
                              hipStream_t stream) {
    const void* x  = d_in[0];
    const int* src = (const int*)d_in[1];
    const int* dst = (const int*)d_in[2];
    const void* Wp = d_in[3];
    const void* bp = d_in[4];
    const void* Wl = d_in[5];
    const void* bl = d_in[6];

    fp16*  h        = (fp16*)d_ws;                       // NN*HD fp16 (12.8 MB)
    fp16*  p        = h + (size_t)NN * HD;               // NN*HD fp16 (12.8 MB), quartered
    float* norm_src = (float*)(p + (size_t)NN * HD);     // NN
    float* norm_dst = norm_src + NN;                     // NN
    int*   row_ofs  = (int*)(norm_dst + NN);             // NN+1
    int*   bsum     = row_ofs + NN + 1;                  // 256
    int*   csr_src  = bsum + 256;                        // EE (3.2 MB)
    int*   deg      = csr_src + EE;                      // NN
    int*   order    = deg + NN;                          // NN
    int*   flag     = order + NN;                        // 1
    fp16*  wbuf     = (fp16*)(flag + 1);                 // 57344 fp16 (114 KB)
    fp16*  wpT      = wbuf;                              // 128x64
    fp16*  wlT      = wbuf + 8192;                       // 3 x 128x128

    // Transient aliases (lifetimes disjoint from h/p by launch order):
    unsigned* PD    = (unsigned*)p;                      // KCH*NPART*PWORDS (3.2 MB)
    unsigned* PS    = PD + (size_t)KCH * NPART * PWORDS; // 3.2 MB (both fit in p)
    int*      start = (int*)h;                           // KCH*NN (6.4 MB, fits in h)

    size_t need = (size_t)((char*)(wbuf + 57344) - (char*)d_ws);
    if (ws_size < need) {
        fill_sentinel<<<(out_size + 255) / 256, 256, 0, stream>>>((bf16*)d_out, out_size);
        return;
    }

    const int MB = (NN + 63) / 64;    // 782

    detect_kernel<<<1, 64, 0, stream>>>((const unsigned short*)x, flag);
    wconv_kernel<<<224, 256, 0, stream>>>(Wp, Wl, flag, wbuf);
    histA_kernel<<<2 * NPART * KCH, 256, 0, stream>>>(src, dst, PD, PS);
    normscanB_kernel<<<NB, 256, 0, stream>>>(PD, PS, norm_src, norm_dst, deg, row_ofs, bsum);
    dsort_kernel<<<1, 256, 0, stream>>>(deg, order);
    scan3_kernel<<<NB, 256, 0, stream>>>(row_ofs, bsum, PD, start);
    placeC_kernel<<<NPART * KCH, 256, 0, stream>>>(src, dst, start, csr_src);

    // h = relu(x @ Wp + bp)   [MFMA, LDS-free]
    proj_kernel<<<MB, 256, 0, stream>>>(x, wpT, bp, flag, h);

    for (int l = 0; l < 3; ++l) {
        // p4 = norm_src ⊙ (h @ Wl), column-quartered   [MFMA, LDS-free]
        pgemm_kernel<<<MB, 256, 0, stream>>>(h, wlT + (size_t)l * 16384, norm_src, p);
        // h_next = relu(norm_dst ⊙ (A @ p) + bl), degree-sorted node order
        gather_kernel<<<8 * GQB, 256, 0, stream>>>(
            p, row_ofs, csr_src, order, norm_dst, bl, l * HD, flag,
            h, d_out, (l == 2) ? 1 : 0);
    }
}

// Round 5
// 420.593 us; speedup vs baseline: 1.2111x; 1.2111x over previous
//
#include <hip/hip_runtime.h>
#include <hip/hip_bf16.h>

#define NN 50000
#define EE 800000
#define IND 64
#define HD 128

#define KCH 64            // edge chunks [R2-proven]
#define CHUNK 12500       // EE / KCH
#define NPART 4           // node partitions
#define PART_N 12500      // NN / NPART
#define PWORDS 6250       // PART_N / 2 (16-bit packed pairs)
#define NB 196            // ceil(NN/256)

#define GQB 391           // gather: grid = 8*GQB = 3128; 782 blocks/quarter, 64 nodes/block

typedef __hip_bfloat16 bf16;
typedef _Float16 fp16;
typedef _Float16 half8 __attribute__((ext_vector_type(8)));
typedef short short8 __attribute__((ext_vector_type(8)));
typedef __attribute__((ext_vector_type(4))) float f32x4;

__device__ __forceinline__ float loadT(const void* p, size_t i, int f32) {
    if (f32) return ((const float*)p)[i];
    return __bfloat162float(((const bf16*)p)[i]);
}

__device__ __forceinline__ float b2f_raw(short s) {
    return __uint_as_float(((unsigned int)(unsigned short)s) << 16);
}

// flag=1 if float inputs are fp32, flag=0 if bf16.
__global__ void detect_kernel(const unsigned short* __restrict__ xraw,
                              int* __restrict__ flag) {
    if (threadIdx.x == 0) {
        int f = 0;
        for (int i = 0; i < 256; i += 2) {
            unsigned int w = ((unsigned int)xraw[i]) << 16;
            float a = fabsf(__uint_as_float(w));
            if (!(a <= 1.0e6f)) f = 1;
        }
        *flag = f;
    }
}

__global__ void fill_sentinel(bf16* __restrict__ out, int n) {
    int i = blockIdx.x * 256 + threadIdx.x;
    if (i < n) out[i] = __float2bfloat16(0.123f);
}

// One-time weight convert+transpose to fp16: WpT[col][k] (128x64) then
// WlT[l][col][k] (3 x 128x128). Total 57344 fp16 = 114KB, L2-resident after.
__global__ __launch_bounds__(256) void wconv_kernel(const void* __restrict__ Wp,
                                                    const void* __restrict__ Wl,
                                                    const int* __restrict__ flag,
                                                    fp16* __restrict__ wbuf) {
    int f32 = *flag;
    int i = blockIdx.x * 256 + threadIdx.x;
    if (i < 8192) {
        int col = i >> 6, k = i & 63;
        wbuf[col * 64 + k] = (fp16)loadT(Wp, (size_t)k * 128 + col, f32);
    } else if (i < 57344) {
        int j = i - 8192;
        int l = j >> 14;
        int r = j & 16383;
        int col = r >> 7, k = r & 127;
        wbuf[8192 + l * 16384 + col * 128 + k] =
            (fp16)loadT(Wl, (size_t)l * 16384 + (size_t)k * 128 + col, f32);
    }
}

// Chunked LDS histograms, zero global atomics. [R2-proven; R3's global-atomic
// variant was 10x slower — device-scope atomics serialize across XCDs]
__global__ __launch_bounds__(256) void histA_kernel(const int* __restrict__ src,
                                                    const int* __restrict__ dst,
                                                    unsigned* __restrict__ PD,
                                                    unsigned* __restrict__ PS) {
    int b = blockIdx.x;
    int stream = b >> 8;
    int part = (b >> 6) & 3;
    int k = b & 63;
    const int* ebuf = stream ? src : dst;
    unsigned* out = (stream ? PS : PD) + (size_t)(k * NPART + part) * PWORDS;
    __shared__ unsigned sh[PWORDS];
    for (int w = threadIdx.x; w < PWORDS; w += 256) sh[w] = 0;
    __syncthreads();
    int base = k * CHUNK;
    int pb = part * PART_N;
    for (int i = threadIdx.x; i < CHUNK; i += 256) {
        int n = ebuf[base + i];
        unsigned r = (unsigned)(n - pb);
        if (r < PART_N)
            atomicAdd(&sh[r >> 1], 1u << ((r & 1) * 16));
    }
    __syncthreads();
    for (int w = threadIdx.x; w < PWORDS; w += 256) out[w] = sh[w];
}

// Sum chunk partials -> degrees -> norms (+ raw in-degree for the sorter);
// block-scan deg_in; raw block totals to bsum.
__global__ __launch_bounds__(256) void normscanB_kernel(const unsigned* __restrict__ PD,
                                                        const unsigned* __restrict__ PS,
                                                        float* __restrict__ norm_src,
                                                        float* __restrict__ norm_dst,
                                                        int* __restrict__ degw,
                                                        int* __restrict__ row_ofs,
                                                        int* __restrict__ bsum) {
    __shared__ int sm[256];
    int t = threadIdx.x;
    int i = blockIdx.x * 256 + t;
    int d = 0;
    if (i < NN) {
        int part = i / PART_N;
        unsigned r = (unsigned)(i - part * PART_N);
        int w = r >> 1, shf = (r & 1) * 16;
        int s = 0;
#pragma unroll
        for (int k = 0; k < KCH; ++k) {
            d += (PD[(size_t)(k * NPART + part) * PWORDS + w] >> shf) & 0xffff;
            s += (PS[(size_t)(k * NPART + part) * PWORDS + w] >> shf) & 0xffff;
        }
        norm_src[i] = rsqrtf((float)(s < 1 ? 1 : s));
        norm_dst[i] = rsqrtf((float)(d < 1 ? 1 : d));
        degw[i] = d;
    }
    sm[t] = d;
    __syncthreads();
    for (int ofs = 1; ofs < 256; ofs <<= 1) {
        int add = (t >= ofs) ? sm[t - ofs] : 0;
        __syncthreads();
        sm[t] += add;
        __syncthreads();
    }
    if (i < NN) row_ofs[i] = sm[t] - d;
    if (t == 255) bsum[blockIdx.x] = sm[255];
}

// --- Parallel counting sort by in-degree (R4's 91us single-block sort was the
// regression; same semantics at ~5us via 3 kernels). ---

// 1) Per-block degree histograms (256 nodes/block, 256 bins).
__global__ __launch_bounds__(256) void dhist_kernel(const int* __restrict__ deg,
                                                    int* __restrict__ bh) {
    __shared__ int hist[256];
    int t = threadIdx.x;
    hist[t] = 0;
    __syncthreads();
    int i = blockIdx.x * 256 + t;
    if (i < NN) {
        int d = deg[i];
        if (d > 255) d = 255;
        atomicAdd(&hist[d], 1);
    }
    __syncthreads();
    bh[blockIdx.x * 256 + t] = hist[t];
}

// 2) Single block: thread t owns bin t; exclusive prefix over blocks (bh
// becomes per-block offsets), then exclusive scan over bin totals.
__global__ __launch_bounds__(256) void dscan_kernel(int* __restrict__ bh,
                                                    int* __restrict__ binstart) {
    int t = threadIdx.x;
    int run = 0;
    for (int b = 0; b < NB; ++b) {
        int v = bh[b * 256 + t];
        bh[b * 256 + t] = run;
        run += v;
    }
    __shared__ int sc[256];
    sc[t] = run;
    __syncthreads();
    for (int ofs = 1; ofs < 256; ofs <<= 1) {
        int add = (t >= ofs) ? sc[t - ofs] : 0;
        __syncthreads();
        sc[t] += add;
        __syncthreads();
    }
    binstart[t] = sc[t] - run;
}

// 3) Placement: LDS cursors seeded binstart[bin]+blockofs; rank via LDS atomic.
__global__ __launch_bounds__(256) void dplace_kernel(const int* __restrict__ deg,
                                                     const int* __restrict__ bh,
                                                     const int* __restrict__ binstart,
                                                     int* __restrict__ order) {
    __shared__ int cur[256];
    int t = threadIdx.x;
    cur[t] = binstart[t] + bh[blockIdx.x * 256 + t];
    __syncthreads();
    int i = blockIdx.x * 256 + t;
    if (i < NN) {
        int d = deg[i];
        if (d > 255) d = 255;
        int pos = atomicAdd(&cur[d], 1);
        order[pos] = i;
    }
}

// Finalize row_ofs (self-computed block prefix over bsum);
// emit per-chunk absolute bucket cursors start[k][n].
__global__ __launch_bounds__(256) void scan3_kernel(int* __restrict__ row_ofs,
                                                    const int* __restrict__ bsum,
                                                    const unsigned* __restrict__ PD,
                                                    int* __restrict__ start) {
    __shared__ int sp[256];
    int t = threadIdx.x;
    sp[t] = (t < NB && t < (int)blockIdx.x) ? bsum[t] : 0;
    __syncthreads();
    for (int o = 128; o > 0; o >>= 1) {
        if (t < o) sp[t] += sp[t + o];
        __syncthreads();
    }
    int pref = sp[0];
    int i = blockIdx.x * 256 + t;
    if (i < NN) {
        int v = row_ofs[i] + pref;
        row_ofs[i] = v;
        int part = i / PART_N;
        unsigned r = (unsigned)(i - part * PART_N);
        int w = r >> 1, shf = (r & 1) * 16;
        int run = v;
#pragma unroll
        for (int k = 0; k < KCH; ++k) {
            start[(size_t)k * NN + i] = run;
            run += (PD[(size_t)(k * NPART + part) * PWORDS + w] >> shf) & 0xffff;
        }
    }
    if (i == 0) row_ofs[NN] = EE;
}

// CSR placement via LDS rank; no global atomics. [R2-proven]
__global__ __launch_bounds__(256) void placeC_kernel(const int* __restrict__ src,
                                                     const int* __restrict__ dst,
                                                     const int* __restrict__ start,
                                                     int* __restrict__ csr_src) {
    int b = blockIdx.x;
    int part = b >> 6;
    int k = b & 63;
    __shared__ unsigned sh[PWORDS];
    for (int w = threadIdx.x; w < PWORDS; w += 256) sh[w] = 0;
    __syncthreads();
    int base = k * CHUNK;
    int pb = part * PART_N;
    for (int i = threadIdx.x; i < CHUNK; i += 256) {
        int n = dst[base + i];
        unsigned r = (unsigned)(n - pb);
        if (r < PART_N) {
            unsigned shf = (r & 1) * 16;
            unsigned old = atomicAdd(&sh[r >> 1], 1u << shf);
            int local = (int)((old >> shf) & 0xffff);
            int pos = start[(size_t)k * NN + n] + local;
            csr_src[pos] = src[base + i];
        }
    }
}

// LDS-free MFMA proj: h = fp16(relu(x @ Wp + bp)). 64 rows/block, 4 waves.
__global__ __launch_bounds__(256) void proj_kernel(const void* __restrict__ x,
                                                   const fp16* __restrict__ wpT,
                                                   const void* __restrict__ bp,
                                                   const int* __restrict__ flag,
                                                   fp16* __restrict__ h) {
    int f32 = *flag;
    int tid = threadIdx.x;
    int w = tid >> 6;
    int lane = tid & 63;
    int m = lane & 15;
    int q = lane >> 4;
    int row0 = blockIdx.x * 64 + w * 16;

    int rowA = row0 + m;
    if (rowA > NN - 1) rowA = NN - 1;
    half8 a0, a1;
    if (!f32) {
        short8 r0 = *(const short8*)((const short*)x + (size_t)rowA * IND + q * 8);
        short8 r1 = *(const short8*)((const short*)x + (size_t)rowA * IND + 32 + q * 8);
#pragma unroll
        for (int j = 0; j < 8; ++j) {
            a0[j] = (fp16)b2f_raw(r0[j]);
            a1[j] = (fp16)b2f_raw(r1[j]);
        }
    } else {
#pragma unroll
        for (int j = 0; j < 8; ++j) {
            a0[j] = (fp16)((const float*)x)[(size_t)rowA * IND + q * 8 + j];
            a1[j] = (fp16)((const float*)x)[(size_t)rowA * IND + 32 + q * 8 + j];
        }
    }

#pragma unroll
    for (int t = 0; t < 8; ++t) {
        int col = t * 16 + m;
        const fp16* bt = wpT + (size_t)col * 64 + q * 8;
        f32x4 c = {0.f, 0.f, 0.f, 0.f};
        c = __builtin_amdgcn_mfma_f32_16x16x32_f16(a0, *(const half8*)bt, c, 0, 0, 0);
        c = __builtin_amdgcn_mfma_f32_16x16x32_f16(a1, *(const half8*)(bt + 32), c, 0, 0, 0);
        float bv = loadT(bp, col, f32);
#pragma unroll
        for (int r = 0; r < 4; ++r) {
            int row = row0 + q * 4 + r;
            if (row < NN)
                h[(size_t)row * HD + col] = (fp16)fmaxf(c[r] + bv, 0.f);
        }
    }
}

// LDS-free MFMA pgemm: p4[quarter][row][0..31] = norm_src[row] * (h[row,:] @ Wl),
// column-quartered layout. col = t*16+m -> quarter = t>>1, within = (t&1)*16+m.
__global__ __launch_bounds__(256) void pgemm_kernel(const fp16* __restrict__ h,
                                                    const fp16* __restrict__ wT,
                                                    const float* __restrict__ norm_src,
                                                    fp16* __restrict__ p) {
    int tid = threadIdx.x;
    int w = tid >> 6;
    int lane = tid & 63;
    int m = lane & 15;
    int q = lane >> 4;
    int row0 = blockIdx.x * 64 + w * 16;

    int rowA = row0 + m;
    if (rowA > NN - 1) rowA = NN - 1;
    const fp16* Arow = h + (size_t)rowA * 128 + q * 8;
    half8 a[4];
#pragma unroll
    for (int kk = 0; kk < 4; ++kk) a[kk] = *(const half8*)(Arow + kk * 32);

    float ns[4];
#pragma unroll
    for (int r = 0; r < 4; ++r) {
        int row = row0 + q * 4 + r;
        ns[r] = norm_src[row < NN ? row : NN - 1];
    }

#pragma unroll
    for (int t = 0; t < 8; ++t) {
        int col = t * 16 + m;
        const fp16* bt = wT + (size_t)col * 128 + q * 8;
        f32x4 c = {0.f, 0.f, 0.f, 0.f};
#pragma unroll
        for (int kk = 0; kk < 4; ++kk) {
            half8 b = *(const half8*)(bt + kk * 32);
            c = __builtin_amdgcn_mfma_f32_16x16x32_f16(a[kk], b, c, 0, 0, 0);
        }
        size_t qbase = ((size_t)(t >> 1) * NN) * 32 + (size_t)((t & 1) * 16 + m);
#pragma unroll
        for (int r = 0; r < 4; ++r) {
            int row = row0 + q * 4 + r;
            if (row < NN)
                p[qbase + (size_t)row * 32] = (fp16)(c[r] * ns[r]);
        }
    }
}

// Quartered gather over DEGREE-SORTED node order: waves get degree-uniform
// node groups -> minimal masked-lane waste in the edge loop.
__global__ __launch_bounds__(256) void gather_kernel(const fp16* __restrict__ p,
                                                     const int* __restrict__ row_ofs,
                                                     const int* __restrict__ csr_src,
                                                     const int* __restrict__ order,
                                                     const float* __restrict__ norm_dst,
                                                     const void* __restrict__ bias,
                                                     int bofs,
                                                     const int* __restrict__ flag,
                                                     fp16* __restrict__ h_out,
                                                     void* __restrict__ outv,
                                                     int is_final) {
    int f32 = *flag;
    int bid = blockIdx.x;
    int s8 = bid & 7;
    int q = s8 >> 1;
    int nodeblock = (bid >> 3) * 2 + (s8 & 1);
    int g = threadIdx.x >> 2;
    int c = threadIdx.x & 3;
    int pos = nodeblock * 64 + g;
    if (pos >= NN) return;
    int n = order[pos];

    const fp16* pq = p + ((size_t)q * NN) * 32 + c * 8;
    int e0 = row_ofs[n];
    int e1 = row_ofs[n + 1];
    float acc[8] = {0.f, 0.f, 0.f, 0.f, 0.f, 0.f, 0.f, 0.f};
    int e = e0;
    for (; e + 7 < e1; e += 8) {
        int s[8];
#pragma unroll
        for (int u = 0; u < 8; ++u) s[u] = __builtin_nontemporal_load(csr_src + e + u);
        half8 v[8];
#pragma unroll
        for (int u = 0; u < 8; ++u)
            v[u] = *(const half8*)(pq + (size_t)s[u] * 32);
#pragma unroll
        for (int j = 0; j < 8; ++j)
            acc[j] += (((float)v[0][j] + (float)v[1][j]) + ((float)v[2][j] + (float)v[3][j])) +
                      (((float)v[4][j] + (float)v[5][j]) + ((float)v[6][j] + (float)v[7][j]));
    }
    for (; e + 3 < e1; e += 4) {
        int s0 = __builtin_nontemporal_load(csr_src + e);
        int s1 = __builtin_nontemporal_load(csr_src + e + 1);
        int s2 = __builtin_nontemporal_load(csr_src + e + 2);
        int s3 = __builtin_nontemporal_load(csr_src + e + 3);
        half8 v0 = *(const half8*)(pq + (size_t)s0 * 32);
        half8 v1 = *(const half8*)(pq + (size_t)s1 * 32);
        half8 v2 = *(const half8*)(pq + (size_t)s2 * 32);
        half8 v3 = *(const half8*)(pq + (size_t)s3 * 32);
#pragma unroll
        for (int j = 0; j < 8; ++j)
            acc[j] += ((float)v0[j] + (float)v1[j]) + ((float)v2[j] + (float)v3[j]);
    }
    for (; e < e1; ++e) {
        int s0 = __builtin_nontemporal_load(csr_src + e);
        half8 v0 = *(const half8*)(pq + (size_t)s0 * 32);
#pragma unroll
        for (int j = 0; j < 8; ++j) acc[j] += (float)v0[j];
    }

    float nd = norm_dst[n];
    int colbase = q * 32 + c * 8;
    size_t base = (size_t)n * HD + colbase;
    if (is_final) {
        if (f32) {
            f32x4 o0, o1;
#pragma unroll
            for (int j = 0; j < 4; ++j) {
                float bv = loadT(bias, (size_t)bofs + colbase + j, f32);
                o0[j] = fmaxf(acc[j] * nd + bv, 0.0f);
            }
#pragma unroll
            for (int j = 0; j < 4; ++j) {
                float bv = loadT(bias, (size_t)bofs + colbase + 4 + j, f32);
                o1[j] = fmaxf(acc[4 + j] * nd + bv, 0.0f);
            }
            __builtin_nontemporal_store(o0, (f32x4*)((float*)outv + base));
            __builtin_nontemporal_store(o1, (f32x4*)((float*)outv + base + 4));
        } else {
            short8 ov;
#pragma unroll
            for (int j = 0; j < 8; ++j) {
                float bv = loadT(bias, (size_t)bofs + colbase + j, f32);
                bf16 t = __float2bfloat16(fmaxf(acc[j] * nd + bv, 0.0f));
                ov[j] = *reinterpret_cast<short*>(&t);
            }
            __builtin_nontemporal_store(ov, (short8*)((bf16*)outv + base));
        }
    } else {
        half8 hv;
#pragma unroll
        for (int j = 0; j < 8; ++j) {
            float bv = loadT(bias, (size_t)bofs + colbase + j, f32);
            hv[j] = (fp16)fmaxf(acc[j] * nd + bv, 0.0f);
        }
        __builtin_nontemporal_store(hv, (half8*)(h_out + base));
    }
}

extern "C" void kernel_launch(void* const* d_in, const int* in_sizes, int n_in,
                              void* d_out, int out_size, void* d_ws, size_t ws_size,
                              hipStream_t stream) {
    const void* x  = d_in[0];
    const int* src = (const int*)d_in[1];
    const int* dst = (const int*)d_in[2];
    const void* Wp = d_in[3];
    const void* bp = d_in[4];
    const void* Wl = d_in[5];
    const void* bl = d_in[6];

    fp16*  h        = (fp16*)d_ws;                       // NN*HD fp16 (12.8 MB)
    fp16*  p        = h + (size_t)NN * HD;               // NN*HD fp16 (12.8 MB), quartered
    float* norm_src = (float*)(p + (size_t)NN * HD);     // NN
    float* norm_dst = norm_src + NN;                     // NN
    int*   row_ofs  = (int*)(norm_dst + NN);             // NN+1
    int*   bsum     = row_ofs + NN + 1;                  // 256
    int*   csr_src  = bsum + 256;                        // EE (3.2 MB)
    int*   deg      = csr_src + EE;                      // NN
    int*   order    = deg + NN;                          // NN
    int*   bh       = order + NN;                        // NB*256 (~200 KB)
    int*   binstart = bh + NB * 256;                     // 256
    int*   flag     = binstart + 256;                    // 1
    fp16*  wbuf     = (fp16*)(flag + 1);                 // 57344 fp16 (114 KB)
    fp16*  wpT      = wbuf;                              // 128x64
    fp16*  wlT      = wbuf + 8192;                       // 3 x 128x128

    // Transient aliases (lifetimes disjoint from h/p by launch order):
    unsigned* PD    = (unsigned*)p;                      // KCH*NPART*PWORDS (6.4 MB)
    unsigned* PS    = PD + (size_t)KCH * NPART * PWORDS; // (PD+PS == p exactly)
    int*      start = (int*)h;                           // KCH*NN (== h exactly)

    size_t need = (size_t)((char*)(wbuf + 57344) - (char*)d_ws);
    if (ws_size < need) {
        fill_sentinel<<<(out_size + 255) / 256, 256, 0, stream>>>((bf16*)d_out, out_size);
        return;
    }

    const int MB = (NN + 63) / 64;    // 782

    detect_kernel<<<1, 64, 0, stream>>>((const unsigned short*)x, flag);
    wconv_kernel<<<224, 256, 0, stream>>>(Wp, Wl, flag, wbuf);
    histA_kernel<<<2 * NPART * KCH, 256, 0, stream>>>(src, dst, PD, PS);
    normscanB_kernel<<<NB, 256, 0, stream>>>(PD, PS, norm_src, norm_dst, deg, row_ofs, bsum);
    dhist_kernel<<<NB, 256, 0, stream>>>(deg, bh);
    dscan_kernel<<<1, 256, 0, stream>>>(bh, binstart);
    dplace_kernel<<<NB, 256, 0, stream>>>(deg, bh, binstart, order);
    scan3_kernel<<<NB, 256, 0, stream>>>(row_ofs, bsum, PD, start);
    placeC_kernel<<<NPART * KCH, 256, 0, stream>>>(src, dst, start, csr_src);

    // h = relu(x @ Wp + bp)   [MFMA, LDS-free]
    proj_kernel<<<MB, 256, 0, stream>>>(x, wpT, bp, flag, h);

    for (int l = 0; l < 3; ++l) {
        // p4 = norm_src ⊙ (h @ Wl), column-quartered   [MFMA, LDS-free]
        pgemm_kernel<<<MB, 256, 0, stream>>>(h, wlT + (size_t)l * 16384, norm_src, p);
        // h_next = relu(norm_dst ⊙ (A @ p) + bl), degree-sorted node order
        gather_kernel<<<8 * GQB, 256, 0, stream>>>(
            p, row_ofs, csr_src, order, norm_dst, bl, l * HD, flag,
            h, d_out, (l == 2) ? 1 : 0);
    }
}

// Round 6
// 387.920 us; speedup vs baseline: 1.3131x; 1.0842x over previous
//
#include <hip/hip_runtime.h>
#include <hip/hip_bf16.h>

#define NN 50000
#define EE 800000
#define IND 64
#define HD 128

#define KCH 64            // edge chunks
#define CHUNK 12500       // EE / KCH
#define NPART 4           // node partitions
#define PART_N 12500      // NN / NPART
#define PWORDS 6250       // PART_N / 2 (16-bit packed pairs)
#define NB 196            // ceil(NN/256)

typedef __hip_bfloat16 bf16;
typedef _Float16 fp16;
typedef _Float16 half8 __attribute__((ext_vector_type(8)));
typedef short short8 __attribute__((ext_vector_type(8)));
typedef __attribute__((ext_vector_type(4))) float f32x4;

__device__ __forceinline__ float loadT(const void* p, size_t i, int f32) {
    if (f32) return ((const float*)p)[i];
    return __bfloat162float(((const bf16*)p)[i]);
}

__device__ __forceinline__ float b2f_raw(short s) {
    return __uint_as_float(((unsigned int)(unsigned short)s) << 16);
}

// flag=1 if float inputs are fp32, flag=0 if bf16.
__global__ void detect_kernel(const unsigned short* __restrict__ xraw,
                              int* __restrict__ flag) {
    if (threadIdx.x == 0) {
        int f = 0;
        for (int i = 0; i < 256; i += 2) {
            unsigned int w = ((unsigned int)xraw[i]) << 16;
            float a = fabsf(__uint_as_float(w));
            if (!(a <= 1.0e6f)) f = 1;
        }
        *flag = f;
    }
}

__global__ void fill_sentinel(bf16* __restrict__ out, int n) {
    int i = blockIdx.x * 256 + threadIdx.x;
    if (i < n) out[i] = __float2bfloat16(0.123f);
}

// One-time weight convert+transpose to fp16: WpT[col][k] (128x64) then
// WlT[l][col][k] (3 x 128x128). Total 57344 fp16 = 114KB, L2-resident after.
__global__ __launch_bounds__(256) void wconv_kernel(const void* __restrict__ Wp,
                                                    const void* __restrict__ Wl,
                                                    const int* __restrict__ flag,
                                                    fp16* __restrict__ wbuf) {
    int f32 = *flag;
    int i = blockIdx.x * 256 + threadIdx.x;
    if (i < 8192) {
        int col = i >> 6, k = i & 63;
        wbuf[col * 64 + k] = (fp16)loadT(Wp, (size_t)k * 128 + col, f32);
    } else if (i < 57344) {
        int j = i - 8192;
        int l = j >> 14;
        int r = j & 16383;
        int col = r >> 7, k = r & 127;
        wbuf[8192 + l * 16384 + col * 128 + k] =
            (fp16)loadT(Wl, (size_t)l * 16384 + (size_t)k * 128 + col, f32);
    }
}

// Chunked LDS histograms, zero global atomics. [R11-proven]
__global__ __launch_bounds__(256) void histA_kernel(const int* __restrict__ src,
                                                    const int* __restrict__ dst,
                                                    unsigned* __restrict__ PD,
                                                    unsigned* __restrict__ PS) {
    int b = blockIdx.x;
    int stream = b >> 8;
    int part = (b >> 6) & 3;
    int k = b & 63;
    const int* ebuf = stream ? src : dst;
    unsigned* out = (stream ? PS : PD) + (size_t)(k * NPART + part) * PWORDS;
    __shared__ unsigned sh[PWORDS];
    for (int w = threadIdx.x; w < PWORDS; w += 256) sh[w] = 0;
    __syncthreads();
    int base = k * CHUNK;
    int pb = part * PART_N;
    for (int i = threadIdx.x; i < CHUNK; i += 256) {
        int n = ebuf[base + i];
        unsigned r = (unsigned)(n - pb);
        if (r < PART_N)
            atomicAdd(&sh[r >> 1], 1u << ((r & 1) * 16));
    }
    __syncthreads();
    for (int w = threadIdx.x; w < PWORDS; w += 256) out[w] = sh[w];
}

// Sum chunk partials -> degrees -> norms; block-scan deg_in; raw block totals to bsum.
__global__ __launch_bounds__(256) void normscanB_kernel(const unsigned* __restrict__ PD,
                                                        const unsigned* __restrict__ PS,
                                                        float* __restrict__ norm_src,
                                                        float* __restrict__ norm_dst,
                                                        int* __restrict__ row_ofs,
                                                        int* __restrict__ bsum) {
    __shared__ int sm[256];
    int t = threadIdx.x;
    int i = blockIdx.x * 256 + t;
    int d = 0;
    if (i < NN) {
        int part = i / PART_N;
        unsigned r = (unsigned)(i - part * PART_N);
        int w = r >> 1, shf = (r & 1) * 16;
        int s = 0;
#pragma unroll
        for (int k = 0; k < KCH; ++k) {
            d += (PD[(size_t)(k * NPART + part) * PWORDS + w] >> shf) & 0xffff;
            s += (PS[(size_t)(k * NPART + part) * PWORDS + w] >> shf) & 0xffff;
        }
        norm_src[i] = rsqrtf((float)(s < 1 ? 1 : s));
        norm_dst[i] = rsqrtf((float)(d < 1 ? 1 : d));
    }
    sm[t] = d;
    __syncthreads();
    for (int ofs = 1; ofs < 256; ofs <<= 1) {
        int add = (t >= ofs) ? sm[t - ofs] : 0;
        __syncthreads();
        sm[t] += add;
        __syncthreads();
    }
    if (i < NN) row_ofs[i] = sm[t] - d;
    if (t == 255) bsum[blockIdx.x] = sm[255];
}

// Finalize row_ofs (self-computed block prefix over bsum — scan2 eliminated);
// emit per-chunk absolute bucket cursors start[k][n].
__global__ __launch_bounds__(256) void scan3_kernel(int* __restrict__ row_ofs,
                                                    const int* __restrict__ bsum,
                                                    const unsigned* __restrict__ PD,
                                                    int* __restrict__ start) {
    __shared__ int sp[256];
    int t = threadIdx.x;
    sp[t] = (t < NB && t < (int)blockIdx.x) ? bsum[t] : 0;
    __syncthreads();
    for (int o = 128; o > 0; o >>= 1) {
        if (t < o) sp[t] += sp[t + o];
        __syncthreads();
    }
    int pref = sp[0];
    int i = blockIdx.x * 256 + t;
    if (i < NN) {
        int v = row_ofs[i] + pref;
        row_ofs[i] = v;
        int part = i / PART_N;
        unsigned r = (unsigned)(i - part * PART_N);
        int w = r >> 1, shf = (r & 1) * 16;
        int run = v;
#pragma unroll
        for (int k = 0; k < KCH; ++k) {
            start[(size_t)k * NN + i] = run;
            run += (PD[(size_t)(k * NPART + part) * PWORDS + w] >> shf) & 0xffff;
        }
    }
    if (i == 0) row_ofs[NN] = EE;
}

// CSR placement via LDS rank; no global atomics. [R11-proven]
__global__ __launch_bounds__(256) void placeC_kernel(const int* __restrict__ src,
                                                     const int* __restrict__ dst,
                                                     const int* __restrict__ start,
                                                     int* __restrict__ csr_src) {
    int b = blockIdx.x;
    int part = b >> 6;
    int k = b & 63;
    __shared__ unsigned sh[PWORDS];
    for (int w = threadIdx.x; w < PWORDS; w += 256) sh[w] = 0;
    __syncthreads();
    int base = k * CHUNK;
    int pb = part * PART_N;
    for (int i = threadIdx.x; i < CHUNK; i += 256) {
        int n = dst[base + i];
        unsigned r = (unsigned)(n - pb);
        if (r < PART_N) {
            unsigned shf = (r & 1) * 16;
            unsigned old = atomicAdd(&sh[r >> 1], 1u << shf);
            int local = (int)((old >> shf) & 0xffff);
            int pos = start[(size_t)k * NN + n] + local;
            csr_src[pos] = src[base + i];
        }
    }
}

// LDS-free MFMA proj: h = fp16(relu(x @ Wp + bp)). 64 rows/block, 4 waves.
__global__ __launch_bounds__(256) void proj_kernel(const void* __restrict__ x,
                                                   const fp16* __restrict__ wpT,
                                                   const void* __restrict__ bp,
                                                   const int* __restrict__ flag,
                                                   fp16* __restrict__ h) {
    int f32 = *flag;
    int tid = threadIdx.x;
    int w = tid >> 6;
    int lane = tid & 63;
    int m = lane & 15;
    int q = lane >> 4;
    int row0 = blockIdx.x * 64 + w * 16;

    int rowA = row0 + m;
    if (rowA > NN - 1) rowA = NN - 1;
    half8 a0, a1;
    if (!f32) {
        short8 r0 = *(const short8*)((const short*)x + (size_t)rowA * IND + q * 8);
        short8 r1 = *(const short8*)((const short*)x + (size_t)rowA * IND + 32 + q * 8);
#pragma unroll
        for (int j = 0; j < 8; ++j) {
            a0[j] = (fp16)b2f_raw(r0[j]);
            a1[j] = (fp16)b2f_raw(r1[j]);
        }
    } else {
#pragma unroll
        for (int j = 0; j < 8; ++j) {
            a0[j] = (fp16)((const float*)x)[(size_t)rowA * IND + q * 8 + j];
            a1[j] = (fp16)((const float*)x)[(size_t)rowA * IND + 32 + q * 8 + j];
        }
    }

#pragma unroll
    for (int t = 0; t < 8; ++t) {
        int col = t * 16 + m;
        const fp16* bt = wpT + (size_t)col * 64 + q * 8;
        f32x4 c = {0.f, 0.f, 0.f, 0.f};
        c = __builtin_amdgcn_mfma_f32_16x16x32_f16(a0, *(const half8*)bt, c, 0, 0, 0);
        c = __builtin_amdgcn_mfma_f32_16x16x32_f16(a1, *(const half8*)(bt + 32), c, 0, 0, 0);
        float bv = loadT(bp, col, f32);
#pragma unroll
        for (int r = 0; r < 4; ++r) {
            int row = row0 + q * 4 + r;
            if (row < NN)
                h[(size_t)row * HD + col] = (fp16)fmaxf(c[r] + bv, 0.f);
        }
    }
}

// LDS-free MFMA pgemm: p[row,:] = norm_src[row] * (h[row,:] @ Wl).
__global__ __launch_bounds__(256) void pgemm_kernel(const fp16* __restrict__ h,
                                                    const fp16* __restrict__ wT,
                                                    const float* __restrict__ norm_src,
                                                    fp16* __restrict__ p) {
    int tid = threadIdx.x;
    int w = tid >> 6;
    int lane = tid & 63;
    int m = lane & 15;
    int q = lane >> 4;
    int row0 = blockIdx.x * 64 + w * 16;

    int rowA = row0 + m;
    if (rowA > NN - 1) rowA = NN - 1;
    const fp16* Arow = h + (size_t)rowA * 128 + q * 8;
    half8 a[4];
#pragma unroll
    for (int kk = 0; kk < 4; ++kk) a[kk] = *(const half8*)(Arow + kk * 32);

    float ns[4];
#pragma unroll
    for (int r = 0; r < 4; ++r) {
        int row = row0 + q * 4 + r;
        ns[r] = norm_src[row < NN ? row : NN - 1];
    }

#pragma unroll
    for (int t = 0; t < 8; ++t) {
        int col = t * 16 + m;
        const fp16* bt = wT + (size_t)col * 128 + q * 8;
        f32x4 c = {0.f, 0.f, 0.f, 0.f};
#pragma unroll
        for (int kk = 0; kk < 4; ++kk) {
            half8 b = *(const half8*)(bt + kk * 32);
            c = __builtin_amdgcn_mfma_f32_16x16x32_f16(a[kk], b, c, 0, 0, 0);
        }
#pragma unroll
        for (int r = 0; r < 4; ++r) {
            int row = row0 + q * 4 + r;
            if (row < NN)
                p[(size_t)row * 128 + col] = (fp16)(c[r] * ns[r]);
        }
    }
}

// out[n,:] = relu(norm_dst[n] * sum_e p[csr_src[e],:] + bias)  [R0-proven 46.9us:
// at the L2 line-request wall — quartering (R2), XCD-pinning (R2) and
// degree-sorting (R5) all measured flat; 3.2M 64B-line touches/layer is the floor]
__global__ __launch_bounds__(256) void gather_kernel(const fp16* __restrict__ p,
                                                     const int* __restrict__ row_ofs,
                                                     const int* __restrict__ csr_src,
                                                     const float* __restrict__ norm_dst,
                                                     const void* __restrict__ bias,
                                                     int bofs,
                                                     const int* __restrict__ flag,
                                                     fp16* __restrict__ h_out,
                                                     void* __restrict__ outv,
                                                     int is_final) {
    int f32 = *flag;
    int g = threadIdx.x >> 4;
    int c = threadIdx.x & 15;
    int n = blockIdx.x * 16 + g;
    int e0 = row_ofs[n];
    int e1 = row_ofs[n + 1];
    float acc[8] = {0.f, 0.f, 0.f, 0.f, 0.f, 0.f, 0.f, 0.f};
    int e = e0;
    for (; e + 7 < e1; e += 8) {
        int s[8];
#pragma unroll
        for (int u = 0; u < 8; ++u) s[u] = csr_src[e + u];
        half8 v[8];
#pragma unroll
        for (int u = 0; u < 8; ++u)
            v[u] = *(const half8*)(p + (size_t)s[u] * HD + c * 8);
#pragma unroll
        for (int j = 0; j < 8; ++j)
            acc[j] += (((float)v[0][j] + (float)v[1][j]) + ((float)v[2][j] + (float)v[3][j])) +
                      (((float)v[4][j] + (float)v[5][j]) + ((float)v[6][j] + (float)v[7][j]));
    }
    for (; e + 3 < e1; e += 4) {
        int s0 = csr_src[e], s1 = csr_src[e + 1];
        int s2 = csr_src[e + 2], s3 = csr_src[e + 3];
        half8 v0 = *(const half8*)(p + (size_t)s0 * HD + c * 8);
        half8 v1 = *(const half8*)(p + (size_t)s1 * HD + c * 8);
        half8 v2 = *(const half8*)(p + (size_t)s2 * HD + c * 8);
        half8 v3 = *(const half8*)(p + (size_t)s3 * HD + c * 8);
#pragma unroll
        for (int j = 0; j < 8; ++j)
            acc[j] += ((float)v0[j] + (float)v1[j]) + ((float)v2[j] + (float)v3[j]);
    }
    for (; e < e1; ++e) {
        int s0 = csr_src[e];
        half8 v0 = *(const half8*)(p + (size_t)s0 * HD + c * 8);
#pragma unroll
        for (int j = 0; j < 8; ++j) acc[j] += (float)v0[j];
    }
    float nd = norm_dst[n];
#pragma unroll
    for (int j = 0; j < 8; ++j) {
        float bv = loadT(bias, (size_t)bofs + c * 8 + j, f32);
        float v = fmaxf(acc[j] * nd + bv, 0.0f);
        size_t idx = (size_t)n * HD + c * 8 + j;
        if (is_final) {
            if (f32) ((float*)outv)[idx] = v;
            else ((bf16*)outv)[idx] = __float2bfloat16(v);
        } else {
            h_out[idx] = (fp16)v;
        }
    }
}

extern "C" void kernel_launch(void* const* d_in, const int* in_sizes, int n_in,
                              void* d_out, int out_size, void* d_ws, size_t ws_size,
                              hipStream_t stream) {
    const void* x  = d_in[0];
    const int* src = (const int*)d_in[1];
    const int* dst = (const int*)d_in[2];
    const void* Wp = d_in[3];
    const void* bp = d_in[4];
    const void* Wl = d_in[5];
    const void* bl = d_in[6];

    fp16*  h        = (fp16*)d_ws;                       // NN*HD fp16 (12.8 MB)
    fp16*  p        = h + (size_t)NN * HD;               // NN*HD fp16 (12.8 MB)
    float* norm_src = (float*)(p + (size_t)NN * HD);     // NN
    float* norm_dst = norm_src + NN;                     // NN
    int*   row_ofs  = (int*)(norm_dst + NN);             // NN+1
    int*   bsum     = row_ofs + NN + 1;                  // 256
    int*   csr_src  = bsum + 256;                        // EE (3.2 MB)
    int*   flag     = csr_src + EE;                      // 1
    fp16*  wbuf     = (fp16*)(flag + 1);                 // 57344 fp16 (114 KB)
    fp16*  wpT      = wbuf;                              // 128x64
    fp16*  wlT      = wbuf + 8192;                       // 3 x 128x128

    // Transient aliases (lifetimes disjoint from h/p by launch order):
    unsigned* PD    = (unsigned*)p;                      // KCH*NPART*PWORDS
    unsigned* PS    = PD + (size_t)KCH * NPART * PWORDS; // (PD+PS == p exactly)
    int*      start = (int*)h;                           // KCH*NN (== h exactly)

    size_t need = (size_t)((char*)(wbuf + 57344) - (char*)d_ws);
    if (ws_size < need) {
        fill_sentinel<<<(out_size + 255) / 256, 256, 0, stream>>>((bf16*)d_out, out_size);
        return;
    }

    const int MB = (NN + 63) / 64;    // 782

    detect_kernel<<<1, 64, 0, stream>>>((const unsigned short*)x, flag);
    wconv_kernel<<<224, 256, 0, stream>>>(Wp, Wl, flag, wbuf);
    histA_kernel<<<2 * NPART * KCH, 256, 0, stream>>>(src, dst, PD, PS);
    normscanB_kernel<<<NB, 256, 0, stream>>>(PD, PS, norm_src, norm_dst, row_ofs, bsum);
    scan3_kernel<<<NB, 256, 0, stream>>>(row_ofs, bsum, PD, start);
    placeC_kernel<<<NPART * KCH, 256, 0, stream>>>(src, dst, start, csr_src);

    // h = relu(x @ Wp + bp)   [MFMA, LDS-free]
    proj_kernel<<<MB, 256, 0, stream>>>(x, wpT, bp, flag, h);

    for (int l = 0; l < 3; ++l) {
        // p = norm_src ⊙ (h @ Wl)   [MFMA, LDS-free]
        pgemm_kernel<<<MB, 256, 0, stream>>>(h, wlT + (size_t)l * 16384, norm_src, p);
        // h_next = relu(norm_dst ⊙ (A @ p) + bl)
        gather_kernel<<<NN / 16, 256, 0, stream>>>(
            p, row_ofs, csr_src, norm_dst, bl, l * HD, flag,
            h, d_out, (l == 2) ? 1 : 0);
    }
}